// Round 12
// baseline (265.118 us; speedup 1.0000x reference)
//
#include <hip/hip_runtime.h>
#include <stdint.h>

// VectorQuantize on MI355X (gfx950) — bf16x3 MFMA distance-GEMM + argmin.
// Round 12: two independent 4-wave blocks per CU (2x 64KB LDS) so one block's
// LDS-read/stage phase overlaps the other's MFMA burst (m114 co-scheduling).
// Block tile BM=128 x BN=128, wave 64x64 acc[4][4]; X2/E2 ring, stage(s+1)
// issued at step top (full-step latency budget); rt-major XCD mapping.
// d_out: [0..N*DIM) quantized (fp32), [N*DIM..+N) ind (fp32), loss, perplexity.

#define N_VEC 16384
#define M_CODES 8192
#define DIM 256
#define BETA 0.25f

#define NSLICE 4
#define SLICE_CODES 2048
#define BM 128
#define BN 128
#define NPART 8                  // NSLICE * 2 col halves

#define BUFBYTES 32768           // Xh 8K | Xl 8K | Eh 8K | El 8K
#define LDS_TOTAL (2 * BUFBYTES) // 64 KiB -> 2 blocks/CU
#define NSTEPS 128               // 16 ct x 8 kc

typedef __attribute__((ext_vector_type(4))) float f32x4;
typedef __attribute__((ext_vector_type(8))) __bf16 bf16x8;

__device__ __forceinline__ void gll16(const void* g, const void* lds_p) {
    __builtin_amdgcn_global_load_lds(
        (const __attribute__((address_space(1))) uint32_t*)(uintptr_t)g,
        (__attribute__((address_space(3))) uint32_t*)(uint32_t)(uintptr_t)lds_p,
        16, 0, 0);
}
#define SB0() __builtin_amdgcn_sched_barrier(0)

__device__ __forceinline__ ushort f2bf(float f) {
    uint32_t u = __float_as_uint(f);
    return (ushort)((u + 0x7FFFu + ((u >> 16) & 1u)) >> 16);  // RNE
}
__device__ __forceinline__ float bf2f(ushort h) {
    return __uint_as_float(((uint32_t)h) << 16);
}

// ---- fused: split fp32 -> bf16 hi/lo for x and e, e2, zero counts/loss ----
__global__ __launch_bounds__(256) void prep_kernel(
    const float* __restrict__ x, const float* __restrict__ emb,
    ushort* __restrict__ xh, ushort* __restrict__ xl,
    ushort* __restrict__ eh, ushort* __restrict__ el,
    float* __restrict__ e2, unsigned* __restrict__ counts,
    float* __restrict__ loss_acc) {
    if (blockIdx.x < 8) {
        int4 z = {0, 0, 0, 0};
        ((int4*)counts)[blockIdx.x * 256 + threadIdx.x] = z;
        if (blockIdx.x == 0 && threadIdx.x == 0) *loss_acc = 0.0f;
    }
    const int wave = threadIdx.x >> 6;
    const int lane = threadIdx.x & 63;
    const int row = blockIdx.x * 4 + wave;

    const float* src;
    ushort* ph;
    ushort* pl;
    bool is_e;
    int er = row - N_VEC;
    if (row < N_VEC) {
        src = x + (size_t)row * DIM;
        ph = xh + (size_t)row * DIM;
        pl = xl + (size_t)row * DIM;
        is_e = false;
    } else {
        src = emb + (size_t)er * DIM;
        ph = eh + (size_t)er * DIM;
        pl = el + (size_t)er * DIM;
        is_e = true;
    }
    float4 v = *(const float4*)(src + lane * 4);
    ushort h0 = f2bf(v.x), h1 = f2bf(v.y), h2 = f2bf(v.z), h3 = f2bf(v.w);
    ushort l0 = f2bf(v.x - bf2f(h0)), l1 = f2bf(v.y - bf2f(h1));
    ushort l2 = f2bf(v.z - bf2f(h2)), l3 = f2bf(v.w - bf2f(h3));
    *(ushort4*)(ph + lane * 4) = make_ushort4(h0, h1, h2, h3);
    *(ushort4*)(pl + lane * 4) = make_ushort4(l0, l1, l2, l3);
    if (is_e) {
        float s = v.x * v.x + v.y * v.y + v.z * v.z + v.w * v.w;
        #pragma unroll
        for (int off = 32; off; off >>= 1) s += __shfl_xor(s, off);
        if (lane == 0) e2[er] = s;
    }
}

// ------ main: bf16x3 MFMA distance GEMM, 4-wave blocks, X2/E2 ring ----
__global__ __launch_bounds__(256, 2) void vq_mfma_kernel(
    const ushort* __restrict__ xh, const ushort* __restrict__ xl,
    const ushort* __restrict__ eh, const ushort* __restrict__ el,
    const float* __restrict__ e2g, unsigned long long* __restrict__ partials) {
    extern __shared__ char lds[];

    const int t = threadIdx.x;
    const int lane = t & 63;
    const int wv = t >> 6;          // 0..3
    const int lane15 = lane & 15;
    const int l16 = lane >> 4;      // 0..3

    // rt-major mapping: XCD = bid%8 = rt%8 -> slice-siblings co-XCD
    const int rt = blockIdx.x & 127;
    const int slice = blockIdx.x >> 7;   // 0..3
    const int row0 = rt * BM;
    const int cslice0 = slice * SLICE_CODES;

    const int wr0 = (wv & 1) * 64;   // wave row half
    const int wch = wv >> 1;         // wave col half (64 codes)

    // ---- fragment LDS byte bases (swizzle term is f-independent)
    const int swz = ((l16 ^ (lane15 >> 1)) & 3) << 4;
    const int byteA0 = (wr0 + lane15) * 64 + swz;
    const int byteB0 = (wch * 64 + lane15) * 64 + swz;

    // ---- staging: linear LDS dest, inverse-swizzled global source
    // 128 rows x 4 chunks = 512 slots of 16B; wave wv -> slots [wv*128, +128)
    const int s0 = wv * 128 + lane;
    const int s1 = s0 + 64;
    const int r0s = s0 >> 2, r1s = s1 >> 2;
    const int c0s = ((s0 & 3) ^ ((s0 >> 3) & 3)) << 3;   // ushort offset (16B)
    const int c1s = ((s1 & 3) ^ ((s1 >> 3) & 3)) << 3;

    const ushort* pxh_a = xh + (size_t)(row0 + r0s) * DIM + c0s;
    const ushort* pxh_b = xh + (size_t)(row0 + r1s) * DIM + c1s;
    const ushort* pxl_a = xl + (size_t)(row0 + r0s) * DIM + c0s;
    const ushort* pxl_b = xl + (size_t)(row0 + r1s) * DIM + c1s;
    const ushort* peh_a = eh + (size_t)(cslice0 + r0s) * DIM + c0s;
    const ushort* peh_b = eh + (size_t)(cslice0 + r1s) * DIM + c1s;
    const ushort* pel_a = el + (size_t)(cslice0 + r0s) * DIM + c0s;
    const ushort* pel_b = el + (size_t)(cslice0 + r1s) * DIM + c1s;
    const int wdst = wv * 2048;   // wave-uniform LDS dest offset

    auto stage = [&](int bufOff, int s) {   // 8 gll: Xh,Xl,Eh,El
        char* b = lds + bufOff + wdst;
        const int xo = (s & 7) * 32;                               // kc*32 ushorts
        const size_t eo = ((size_t)(s >> 3) << 15) + (s & 7) * 32; // ct*BN*DIM + kc*32
        gll16(pxh_a + xo, b);
        gll16(pxh_b + xo, b + 1024);
        gll16(pxl_a + xo, b + 8192);
        gll16(pxl_b + xo, b + 8192 + 1024);
        gll16(peh_a + eo, b + 16384);
        gll16(peh_b + eo, b + 16384 + 1024);
        gll16(pel_a + eo, b + 24576);
        gll16(pel_b + eo, b + 24576 + 1024);
    };

    float best[16];
    int bidx[16];
    #pragma unroll
    for (int s = 0; s < 16; ++s) { best[s] = __uint_as_float(0x7f800000u); bidx[s] = 0; }

    f32x4 acc[4][4];
    #pragma unroll
    for (int fi = 0; fi < 4; ++fi)
        #pragma unroll
        for (int fj = 0; fj < 4; ++fj) acc[fi][fj] = (f32x4){0.f, 0.f, 0.f, 0.f};

    float e2r[4];

    // prologue: stage step 0 into buffer 0
    stage(0, 0); SB0();

    for (int s = 0; s < NSTEPS; ++s) {
        // entry: stage(s) was issued a full step ago -> near-free drain
        asm volatile("s_waitcnt vmcnt(0)" ::: "memory");
        __builtin_amdgcn_s_barrier();
        SB0();
        // next-step stage into the buffer freed by step s-1's readers
        if (s + 1 < NSTEPS) { stage(((s + 1) & 1) * BUFBYTES, s + 1); SB0(); }
        if ((s & 7) == 0) {
            const int cb = cslice0 + (s >> 3) * BN + wch * 64 + lane15;
            #pragma unroll
            for (int fj = 0; fj < 4; ++fj) e2r[fj] = e2g[cb + fj * 16];
            SB0();
        }

        const char* lb = lds + (s & 1) * BUFBYTES;
        bf16x8 ah[4], alo[4];
        #pragma unroll
        for (int f = 0; f < 4; ++f) {
            ah[f] = *(const bf16x8*)(lb + byteA0 + f * 1024);
            alo[f] = *(const bf16x8*)(lb + 8192 + byteA0 + f * 1024);
        }
        __builtin_amdgcn_s_setprio(1);
        #pragma unroll
        for (int fj = 0; fj < 4; ++fj) {
            bf16x8 bh = *(const bf16x8*)(lb + 16384 + byteB0 + fj * 1024);
            bf16x8 blo = *(const bf16x8*)(lb + 24576 + byteB0 + fj * 1024);
            #pragma unroll
            for (int fi = 0; fi < 4; ++fi)
                acc[fi][fj] = __builtin_amdgcn_mfma_f32_16x16x32_bf16(
                    ah[fi], bh, acc[fi][fj], 0, 0, 0);
            #pragma unroll
            for (int fi = 0; fi < 4; ++fi)
                acc[fi][fj] = __builtin_amdgcn_mfma_f32_16x16x32_bf16(
                    ah[fi], blo, acc[fi][fj], 0, 0, 0);
            #pragma unroll
            for (int fi = 0; fi < 4; ++fi)
                acc[fi][fj] = __builtin_amdgcn_mfma_f32_16x16x32_bf16(
                    alo[fi], bh, acc[fi][fj], 0, 0, 0);
        }
        __builtin_amdgcn_s_setprio(0);

        if ((s & 7) == 7) {
            // epilogue for ct = s>>3: score = e2[c] - 2*dot
            // C/D layout: col = lane15, row = l16*4 + r
            const int ct = s >> 3;
            const int cb = cslice0 + ct * BN + wch * 64 + lane15;
            #pragma unroll
            for (int fj = 0; fj < 4; ++fj) {
                const int c = cb + fj * 16;
                #pragma unroll
                for (int fi = 0; fi < 4; ++fi)
                    #pragma unroll
                    for (int r = 0; r < 4; ++r) {
                        float sc = e2r[fj] - 2.0f * acc[fi][fj][r];
                        const int slot = fi * 4 + r;
                        if (sc < best[slot]) { best[slot] = sc; bidx[slot] = c; }
                    }
            }
            #pragma unroll
            for (int fi = 0; fi < 4; ++fi)
                #pragma unroll
                for (int fj = 0; fj < 4; ++fj)
                    acc[fi][fj] = (f32x4){0.f, 0.f, 0.f, 0.f};
        }
    }

    // reduce across the 16 lanes sharing each row; ties -> lowest index
    #pragma unroll
    for (int slot = 0; slot < 16; ++slot) {
        float v = best[slot];
        int ix = bidx[slot];
        #pragma unroll
        for (int off = 1; off < 16; off <<= 1) {
            float v2 = __shfl_xor(v, off);
            int ix2 = __shfl_xor(ix, off);
            if (v2 < v || (v2 == v && ix2 < ix)) { v = v2; ix = ix2; }
        }
        if (lane15 == 0) {
            int fi = slot >> 2, r = slot & 3;
            int row = row0 + wr0 + fi * 16 + l16 * 4 + r;
            uint32_t u = __float_as_uint(v);
            uint32_t ord = (u & 0x80000000u) ? ~u : (u | 0x80000000u);
            partials[(size_t)(slice * 2 + wch) * N_VEC + row] =
                ((unsigned long long)ord << 32) | (unsigned)ix;
        }
    }
}

// ---------------- fused: per-row min over partials + gather + loss + counts
__global__ __launch_bounds__(256) void finish_kernel(
    const float* __restrict__ x, const float* __restrict__ emb,
    const unsigned long long* __restrict__ partials,
    float* __restrict__ out_ind, float* __restrict__ out_q,
    unsigned* __restrict__ counts, float* __restrict__ loss_acc) {
    __shared__ float partial[4];
    const int wave = threadIdx.x >> 6;
    const int lane = threadIdx.x & 63;
    const int row = blockIdx.x * 4 + wave;

    unsigned long long m = ~0ull;
    if (lane < NPART) m = partials[(size_t)lane * N_VEC + row];
    #pragma unroll
    for (int off = 1; off < NPART; off <<= 1) {
        unsigned long long v = __shfl_xor(m, off);
        if (v < m) m = v;
    }
    m = __shfl(m, 0);
    const int ix = (int)(unsigned)(m & 0xFFFFFFFFull);

    float4 q = *(const float4*)(emb + (size_t)ix * DIM + lane * 4);
    float4 xv = *(const float4*)(x + (size_t)row * DIM + lane * 4);
    *(float4*)(out_q + (size_t)row * DIM + lane * 4) = q;
    float dx = q.x - xv.x, dy = q.y - xv.y, dz = q.z - xv.z, dw = q.w - xv.w;
    float s = dx * dx + dy * dy + dz * dz + dw * dw;
    #pragma unroll
    for (int off = 32; off; off >>= 1) s += __shfl_xor(s, off);
    if (lane == 0) {
        out_ind[row] = (float)ix;
        atomicAdd(&counts[ix], 1u);
        partial[wave] = s;
    }
    __syncthreads();
    if (threadIdx.x == 0)
        atomicAdd(loss_acc, partial[0] + partial[1] + partial[2] + partial[3]);
}

// -------------------------------------------------- entropy / loss finalize
__global__ __launch_bounds__(256) void finalize_kernel(
    const unsigned* __restrict__ counts, const float* __restrict__ loss_acc,
    float* __restrict__ out_scalars) {
    __shared__ float red[256];
    float h = 0.0f;
    for (int c = threadIdx.x; c < M_CODES; c += 256) {
        float p = (float)counts[c] * (1.0f / (float)N_VEC);
        h += p * logf(p + 1e-10f);
    }
    red[threadIdx.x] = h;
    __syncthreads();
    for (int s = 128; s; s >>= 1) {
        if (threadIdx.x < s) red[threadIdx.x] += red[threadIdx.x + s];
        __syncthreads();
    }
    if (threadIdx.x == 0) {
        out_scalars[0] = BETA * loss_acc[0] / (float)(N_VEC * DIM);
        out_scalars[1] = expf(-red[0]);
    }
}

extern "C" void kernel_launch(void* const* d_in, const int* in_sizes, int n_in,
                              void* d_out, int out_size, void* d_ws, size_t ws_size,
                              hipStream_t stream) {
    const float* x = (const float*)d_in[0];
    const float* emb = (const float*)d_in[1];

    float* out = (float*)d_out;
    float* out_q = out;                                   // N*DIM
    float* out_ind = out + (size_t)N_VEC * DIM;           // N
    float* out_scalars = out_ind + N_VEC;                 // 2

    // x hi/lo scratch lives in d_out's quantized region (rewritten by finish)
    ushort* xh = (ushort*)out;                            // 8 MB
    ushort* xl = xh + (size_t)N_VEC * DIM;                // 8 MB

    char* wp = (char*)d_ws;
    ushort* eh = (ushort*)wp;  wp += (size_t)M_CODES * DIM * 2;   // 4 MB
    ushort* el = (ushort*)wp;  wp += (size_t)M_CODES * DIM * 2;   // 4 MB
    float* e2 = (float*)wp;    wp += (size_t)M_CODES * 4;         // 32 KB
    unsigned long long* partials = (unsigned long long*)wp;
    wp += (size_t)NPART * N_VEC * 8;                              // 1 MB
    unsigned* counts = (unsigned*)wp; wp += (size_t)M_CODES * 4;  // 32 KB
    float* loss_acc = (float*)wp;                                 // 4 B

    prep_kernel<<<(N_VEC + M_CODES) / 4, 256, 0, stream>>>(x, emb, xh, xl, eh, el,
                                                           e2, counts, loss_acc);

    hipFuncSetAttribute((const void*)vq_mfma_kernel,
                        hipFuncAttributeMaxDynamicSharedMemorySize, LDS_TOTAL);
    vq_mfma_kernel<<<(N_VEC / BM) * NSLICE, 256, LDS_TOTAL, stream>>>(
        xh, xl, eh, el, e2, partials);

    finish_kernel<<<N_VEC / 4, 256, 0, stream>>>(x, emb, partials, out_ind, out_q,
                                                 counts, loss_acc);
    finalize_kernel<<<1, 256, 0, stream>>>(counts, loss_acc, out_scalars);
}

// Round 13
// 240.005 us; speedup vs baseline: 1.1046x; 1.1046x over previous
//
#include <hip/hip_runtime.h>
#include <stdint.h>

// VectorQuantize on MI355X (gfx950) — bf16x3 MFMA distance-GEMM + argmin.
// Round 13: r8 skeleton (BM=256 x BN=256, wave 64x128 acc[4][8], X3/E2
// counted-vmcnt(4) ring, rt-major XCD mapping) + pinned inline-asm ds_read
// with counted lgkmcnt(2) so the LDS pipe drains under the MFMA bursts
// (compiler sank the reads to just-in-time in r8/r10 -> serial convoy).
// d_out: [0..N*DIM) quantized (fp32), [N*DIM..+N) ind (fp32), loss, perplexity.

#define N_VEC 16384
#define M_CODES 8192
#define DIM 256
#define BETA 0.25f

#define NSLICE 4
#define SLICE_CODES 2048
#define BM 256
#define BN 256
#define NPART 8                  // NSLICE * 2 col groups

#define XSLOT 32768              // xh 16K | xl 16K   (256 rows x 64B)
#define ESLOT 32768              // eh 16K | el 16K   (256 rows x 64B)
#define EBASE (3 * XSLOT)
#define LDS_TOTAL (3 * XSLOT + 2 * ESLOT)   // 163840 = 160 KiB exactly
#define NSTEPS 64                // 8 ct x 8 kc

typedef __attribute__((ext_vector_type(4))) float f32x4;
typedef __attribute__((ext_vector_type(4))) int i32x4;
typedef __attribute__((ext_vector_type(8))) __bf16 bf16x8;

__device__ __forceinline__ void gll16(const void* g, const void* lds_p) {
    __builtin_amdgcn_global_load_lds(
        (const __attribute__((address_space(1))) uint32_t*)(uintptr_t)g,
        (__attribute__((address_space(3))) uint32_t*)(uint32_t)(uintptr_t)lds_p,
        16, 0, 0);
}
#define SB0() __builtin_amdgcn_sched_barrier(0)

// pinned LDS read: volatile asm -> compiler cannot sink it into the MFMA burst
#define DSR(DST, ADDR, OFF) \
    asm volatile("ds_read_b128 %0, %1 offset:" #OFF : "=v"(DST) : "v"(ADDR))
#define LGKM(N) asm volatile("s_waitcnt lgkmcnt(" #N ")" ::: "memory")

__device__ __forceinline__ ushort f2bf(float f) {
    uint32_t u = __float_as_uint(f);
    return (ushort)((u + 0x7FFFu + ((u >> 16) & 1u)) >> 16);  // RNE
}
__device__ __forceinline__ float bf2f(ushort h) {
    return __uint_as_float(((uint32_t)h) << 16);
}

// ---- fused: split fp32 -> bf16 hi/lo for x and e, e2, zero counts/loss ----
__global__ __launch_bounds__(256) void prep_kernel(
    const float* __restrict__ x, const float* __restrict__ emb,
    ushort* __restrict__ xh, ushort* __restrict__ xl,
    ushort* __restrict__ eh, ushort* __restrict__ el,
    float* __restrict__ e2, unsigned* __restrict__ counts,
    float* __restrict__ loss_acc) {
    if (blockIdx.x < 8) {
        int4 z = {0, 0, 0, 0};
        ((int4*)counts)[blockIdx.x * 256 + threadIdx.x] = z;
        if (blockIdx.x == 0 && threadIdx.x == 0) *loss_acc = 0.0f;
    }
    const int wave = threadIdx.x >> 6;
    const int lane = threadIdx.x & 63;
    const int row = blockIdx.x * 4 + wave;

    const float* src;
    ushort* ph;
    ushort* pl;
    bool is_e;
    int er = row - N_VEC;
    if (row < N_VEC) {
        src = x + (size_t)row * DIM;
        ph = xh + (size_t)row * DIM;
        pl = xl + (size_t)row * DIM;
        is_e = false;
    } else {
        src = emb + (size_t)er * DIM;
        ph = eh + (size_t)er * DIM;
        pl = el + (size_t)er * DIM;
        is_e = true;
    }
    float4 v = *(const float4*)(src + lane * 4);
    ushort h0 = f2bf(v.x), h1 = f2bf(v.y), h2 = f2bf(v.z), h3 = f2bf(v.w);
    ushort l0 = f2bf(v.x - bf2f(h0)), l1 = f2bf(v.y - bf2f(h1));
    ushort l2 = f2bf(v.z - bf2f(h2)), l3 = f2bf(v.w - bf2f(h3));
    *(ushort4*)(ph + lane * 4) = make_ushort4(h0, h1, h2, h3);
    *(ushort4*)(pl + lane * 4) = make_ushort4(l0, l1, l2, l3);
    if (is_e) {
        float s = v.x * v.x + v.y * v.y + v.z * v.z + v.w * v.w;
        #pragma unroll
        for (int off = 32; off; off >>= 1) s += __shfl_xor(s, off);
        if (lane == 0) e2[er] = s;
    }
}

// ------ main: bf16x3 MFMA distance GEMM, X3/E2 ring, pinned-read pipeline ----
__global__ __launch_bounds__(512, 1) void vq_mfma_kernel(
    const ushort* __restrict__ xh, const ushort* __restrict__ xl,
    const ushort* __restrict__ eh, const ushort* __restrict__ el,
    const float* __restrict__ e2g, unsigned long long* __restrict__ partials) {
    extern __shared__ char lds[];

    const int t = threadIdx.x;
    const int lane = t & 63;
    const int wv = t >> 6;          // 0..7
    const int lane15 = lane & 15;
    const int l16 = lane >> 4;      // 0..3

    // rt-major mapping: XCD = bid%8 = rt%8 -> slice-siblings co-XCD
    const int rt = blockIdx.x & 63;
    const int slice = blockIdx.x >> 6;   // 0..3
    const int row0 = rt * BM;
    const int cslice0 = slice * SLICE_CODES;

    const int wr0 = (wv & 3) * 64;   // wave row group 0..192
    const int wch = wv >> 2;         // wave col group (128 codes)

    // ---- fragment LDS byte bases (swizzle term is f/fj-independent)
    const int swz = ((l16 ^ (lane15 >> 1)) & 3) << 4;
    const int byteA0 = (wr0 + lane15) * 64 + swz;
    const int byteB0 = (wch * 128 + lane15) * 64 + swz;

    // ---- staging: linear LDS dest, inverse-swizzled global source
    const int s0 = wv * 128 + lane;
    const int s1 = s0 + 64;
    const int r0s = s0 >> 2, r1s = s1 >> 2;
    const int c0s = ((s0 & 3) ^ ((s0 >> 3) & 3)) << 3;
    const int c1s = ((s1 & 3) ^ ((s1 >> 3) & 3)) << 3;

    const ushort* pxh_a = xh + (size_t)(row0 + r0s) * DIM + c0s;
    const ushort* pxh_b = xh + (size_t)(row0 + r1s) * DIM + c1s;
    const ushort* pxl_a = xl + (size_t)(row0 + r0s) * DIM + c0s;
    const ushort* pxl_b = xl + (size_t)(row0 + r1s) * DIM + c1s;
    const ushort* peh_a = eh + (size_t)(cslice0 + r0s) * DIM + c0s;
    const ushort* peh_b = eh + (size_t)(cslice0 + r1s) * DIM + c1s;
    const ushort* pel_a = el + (size_t)(cslice0 + r0s) * DIM + c0s;
    const ushort* pel_b = el + (size_t)(cslice0 + r1s) * DIM + c1s;
    const int wdst = wv * 2048;   // wave-uniform LDS dest offset

    auto stage_X = [&](int slot, int s) {   // 4 gll
        char* b = lds + slot * XSLOT + wdst;
        const int xo = (s & 7) * 32;
        gll16(pxh_a + xo, b);
        gll16(pxh_b + xo, b + 1024);
        gll16(pxl_a + xo, b + 16384);
        gll16(pxl_b + xo, b + 16384 + 1024);
    };
    auto stage_E = [&](int slot, int s) {   // 4 gll
        char* b = lds + EBASE + slot * ESLOT + wdst;
        const size_t eo = ((size_t)(s >> 3) << 16) + (s & 7) * 32;  // ct*BN*DIM + kc*32
        gll16(peh_a + eo, b);
        gll16(peh_b + eo, b + 1024);
        gll16(pel_a + eo, b + 16384);
        gll16(pel_b + eo, b + 16384 + 1024);
    };

    float best[16];
    int bidx[16];
    #pragma unroll
    for (int s = 0; s < 16; ++s) { best[s] = __uint_as_float(0x7f800000u); bidx[s] = 0; }

    f32x4 acc[4][8];
    #pragma unroll
    for (int fi = 0; fi < 4; ++fi)
        #pragma unroll
        for (int fj = 0; fj < 8; ++fj) acc[fi][fj] = (f32x4){0.f, 0.f, 0.f, 0.f};

    float e2r[8];

    // 12 MFMAs of one fj column (hh, hl, lh); PH/PL are raw i32x4 reads
#define BURST(FJ, PH, PL) do {                                           \
    bf16x8 bh_ = __builtin_bit_cast(bf16x8, PH);                         \
    bf16x8 bl_ = __builtin_bit_cast(bf16x8, PL);                         \
    _Pragma("unroll") for (int fi_ = 0; fi_ < 4; ++fi_)                  \
        acc[fi_][FJ] = __builtin_amdgcn_mfma_f32_16x16x32_bf16(          \
            ah[fi_], bh_, acc[fi_][FJ], 0, 0, 0);                        \
    _Pragma("unroll") for (int fi_ = 0; fi_ < 4; ++fi_)                  \
        acc[fi_][FJ] = __builtin_amdgcn_mfma_f32_16x16x32_bf16(          \
            ah[fi_], bl_, acc[fi_][FJ], 0, 0, 0);                        \
    _Pragma("unroll") for (int fi_ = 0; fi_ < 4; ++fi_)                  \
        acc[fi_][FJ] = __builtin_amdgcn_mfma_f32_16x16x32_bf16(          \
            alo[fi_], bh_, acc[fi_][FJ], 0, 0, 0);                       \
    } while (0)

    // prologue FIFO: X(0), E(0), X(1)
    stage_X(0, 0); SB0();
    stage_E(0, 0); SB0();
    stage_X(1, 1); SB0();

    int xsl = 0;  // X slot of current step = s%3
    for (int s = 0; s < NSTEPS; ++s) {
        // entry: drain X(s)+E(s); keep X(s+1) (4) in flight
        if (s == NSTEPS - 1) {
            asm volatile("s_waitcnt vmcnt(0)" ::: "memory");
        } else {
            asm volatile("s_waitcnt vmcnt(4)" ::: "memory");
        }
        __builtin_amdgcn_s_barrier();
        SB0();
        if ((s & 7) == 0) {
            const int cb = cslice0 + (s >> 3) * BN + wch * 128 + lane15;
            #pragma unroll
            for (int fj = 0; fj < 8; ++fj) e2r[fj] = e2g[cb + fj * 16];
            SB0();
        }
        if (s + 1 < NSTEPS) { stage_E((s + 1) & 1, s + 1); SB0(); }
        if (s + 2 < NSTEPS) { stage_X((xsl >= 1) ? xsl - 1 : 2, s + 2); SB0(); }

        const uint32_t vA =
            (uint32_t)(uintptr_t)(lds + xsl * XSLOT) + (uint32_t)byteA0;
        const uint32_t vB =
            (uint32_t)(uintptr_t)(lds + EBASE + (s & 1) * ESLOT) + (uint32_t)byteB0;

        // pinned read issue: 8 A-frags, then B pairs flowing 1 ahead of MFMA
        i32x4 ra0, ra1, ra2, ra3, rl0, rl1, rl2, rl3, paH, paL, pbH, pbL;
        DSR(ra0, vA, 0);     DSR(ra1, vA, 1024);
        DSR(ra2, vA, 2048);  DSR(ra3, vA, 3072);
        DSR(rl0, vA, 16384); DSR(rl1, vA, 17408);
        DSR(rl2, vA, 18432); DSR(rl3, vA, 19456);
        DSR(paH, vB, 0);     DSR(paL, vB, 16384);
        __builtin_amdgcn_s_setprio(1);
        DSR(pbH, vB, 1024);  DSR(pbL, vB, 17408);

        bf16x8 ah[4], alo[4];
        ah[0] = __builtin_bit_cast(bf16x8, ra0);
        ah[1] = __builtin_bit_cast(bf16x8, ra1);
        ah[2] = __builtin_bit_cast(bf16x8, ra2);
        ah[3] = __builtin_bit_cast(bf16x8, ra3);
        alo[0] = __builtin_bit_cast(bf16x8, rl0);
        alo[1] = __builtin_bit_cast(bf16x8, rl1);
        alo[2] = __builtin_bit_cast(bf16x8, rl2);
        alo[3] = __builtin_bit_cast(bf16x8, rl3);

        LGKM(2); SB0(); BURST(0, paH, paL);
        DSR(paH, vB, 2048); DSR(paL, vB, 18432);
        LGKM(2); SB0(); BURST(1, pbH, pbL);
        DSR(pbH, vB, 3072); DSR(pbL, vB, 19456);
        LGKM(2); SB0(); BURST(2, paH, paL);
        DSR(paH, vB, 4096); DSR(paL, vB, 20480);
        LGKM(2); SB0(); BURST(3, pbH, pbL);
        DSR(pbH, vB, 5120); DSR(pbL, vB, 21504);
        LGKM(2); SB0(); BURST(4, paH, paL);
        DSR(paH, vB, 6144); DSR(paL, vB, 22528);
        LGKM(2); SB0(); BURST(5, pbH, pbL);
        DSR(pbH, vB, 7168); DSR(pbL, vB, 23552);
        LGKM(2); SB0(); BURST(6, paH, paL);
        LGKM(0); SB0(); BURST(7, pbH, pbL);
        __builtin_amdgcn_s_setprio(0);
        xsl = (xsl == 2) ? 0 : xsl + 1;

        if ((s & 7) == 7) {
            // epilogue for ct = s>>3: score = e2[c] - 2*dot
            // C/D layout: col = lane15, row = l16*4 + r
            const int ct = s >> 3;
            const int cb = cslice0 + ct * BN + wch * 128 + lane15;
            #pragma unroll
            for (int fj = 0; fj < 8; ++fj) {
                const int c = cb + fj * 16;
                #pragma unroll
                for (int fi = 0; fi < 4; ++fi)
                    #pragma unroll
                    for (int r = 0; r < 4; ++r) {
                        float sc = e2r[fj] - 2.0f * acc[fi][fj][r];
                        const int slot = fi * 4 + r;
                        if (sc < best[slot]) { best[slot] = sc; bidx[slot] = c; }
                    }
            }
            #pragma unroll
            for (int fi = 0; fi < 4; ++fi)
                #pragma unroll
                for (int fj = 0; fj < 8; ++fj)
                    acc[fi][fj] = (f32x4){0.f, 0.f, 0.f, 0.f};
        }
    }
#undef BURST

    // reduce across the 16 lanes sharing each row; ties -> lowest index
    #pragma unroll
    for (int slot = 0; slot < 16; ++slot) {
        float v = best[slot];
        int ix = bidx[slot];
        #pragma unroll
        for (int off = 1; off < 16; off <<= 1) {
            float v2 = __shfl_xor(v, off);
            int ix2 = __shfl_xor(ix, off);
            if (v2 < v || (v2 == v && ix2 < ix)) { v = v2; ix = ix2; }
        }
        if (lane15 == 0) {
            int fi = slot >> 2, r = slot & 3;
            int row = row0 + wr0 + fi * 16 + l16 * 4 + r;
            uint32_t u = __float_as_uint(v);
            uint32_t ord = (u & 0x80000000u) ? ~u : (u | 0x80000000u);
            partials[(size_t)(slice * 2 + wch) * N_VEC + row] =
                ((unsigned long long)ord << 32) | (unsigned)ix;
        }
    }
}

// ---------------- fused: per-row min over partials + gather + loss + counts
__global__ __launch_bounds__(256) void finish_kernel(
    const float* __restrict__ x, const float* __restrict__ emb,
    const unsigned long long* __restrict__ partials,
    float* __restrict__ out_ind, float* __restrict__ out_q,
    unsigned* __restrict__ counts, float* __restrict__ loss_acc) {
    __shared__ float partial[4];
    const int wave = threadIdx.x >> 6;
    const int lane = threadIdx.x & 63;
    const int row = blockIdx.x * 4 + wave;

    unsigned long long m = ~0ull;
    if (lane < NPART) m = partials[(size_t)lane * N_VEC + row];
    #pragma unroll
    for (int off = 1; off < NPART; off <<= 1) {
        unsigned long long v = __shfl_xor(m, off);
        if (v < m) m = v;
    }
    m = __shfl(m, 0);
    const int ix = (int)(unsigned)(m & 0xFFFFFFFFull);

    float4 q = *(const float4*)(emb + (size_t)ix * DIM + lane * 4);
    float4 xv = *(const float4*)(x + (size_t)row * DIM + lane * 4);
    *(float4*)(out_q + (size_t)row * DIM + lane * 4) = q;
    float dx = q.x - xv.x, dy = q.y - xv.y, dz = q.z - xv.z, dw = q.w - xv.w;
    float s = dx * dx + dy * dy + dz * dz + dw * dw;
    #pragma unroll
    for (int off = 32; off; off >>= 1) s += __shfl_xor(s, off);
    if (lane == 0) {
        out_ind[row] = (float)ix;
        atomicAdd(&counts[ix], 1u);
        partial[wave] = s;
    }
    __syncthreads();
    if (threadIdx.x == 0)
        atomicAdd(loss_acc, partial[0] + partial[1] + partial[2] + partial[3]);
}

// -------------------------------------------------- entropy / loss finalize
__global__ __launch_bounds__(256) void finalize_kernel(
    const unsigned* __restrict__ counts, const float* __restrict__ loss_acc,
    float* __restrict__ out_scalars) {
    __shared__ float red[256];
    float h = 0.0f;
    for (int c = threadIdx.x; c < M_CODES; c += 256) {
        float p = (float)counts[c] * (1.0f / (float)N_VEC);
        h += p * logf(p + 1e-10f);
    }
    red[threadIdx.x] = h;
    __syncthreads();
    for (int s = 128; s; s >>= 1) {
        if (threadIdx.x < s) red[threadIdx.x] += red[threadIdx.x + s];
        __syncthreads();
    }
    if (threadIdx.x == 0) {
        out_scalars[0] = BETA * loss_acc[0] / (float)(N_VEC * DIM);
        out_scalars[1] = expf(-red[0]);
    }
}

extern "C" void kernel_launch(void* const* d_in, const int* in_sizes, int n_in,
                              void* d_out, int out_size, void* d_ws, size_t ws_size,
                              hipStream_t stream) {
    const float* x = (const float*)d_in[0];
    const float* emb = (const float*)d_in[1];

    float* out = (float*)d_out;
    float* out_q = out;                                   // N*DIM
    float* out_ind = out + (size_t)N_VEC * DIM;           // N
    float* out_scalars = out_ind + N_VEC;                 // 2

    // x hi/lo scratch lives in d_out's quantized region (rewritten by finish)
    ushort* xh = (ushort*)out;                            // 8 MB
    ushort* xl = xh + (size_t)N_VEC * DIM;                // 8 MB

    char* wp = (char*)d_ws;
    ushort* eh = (ushort*)wp;  wp += (size_t)M_CODES * DIM * 2;   // 4 MB
    ushort* el = (ushort*)wp;  wp += (size_t)M_CODES * DIM * 2;   // 4 MB
    float* e2 = (float*)wp;    wp += (size_t)M_CODES * 4;         // 32 KB
    unsigned long long* partials = (unsigned long long*)wp;
    wp += (size_t)NPART * N_VEC * 8;                              // 1 MB
    unsigned* counts = (unsigned*)wp; wp += (size_t)M_CODES * 4;  // 32 KB
    float* loss_acc = (float*)wp;                                 // 4 B

    prep_kernel<<<(N_VEC + M_CODES) / 4, 256, 0, stream>>>(x, emb, xh, xl, eh, el,
                                                           e2, counts, loss_acc);

    hipFuncSetAttribute((const void*)vq_mfma_kernel,
                        hipFuncAttributeMaxDynamicSharedMemorySize, LDS_TOTAL);
    vq_mfma_kernel<<<(N_VEC / BM) * NSLICE, 512, LDS_TOTAL, stream>>>(
        xh, xl, eh, el, e2, partials);

    finish_kernel<<<N_VEC / 4, 256, 0, stream>>>(x, emb, partials, out_ind, out_q,
                                                 counts, loss_acc);
    finalize_kernel<<<1, 256, 0, stream>>>(counts, loss_acc, out_scalars);
}